// Round 7
// baseline (194.691 us; speedup 1.0000x reference)
//
#include <hip/hip_runtime.h>

typedef __attribute__((ext_vector_type(8))) __bf16 bf16x8;
typedef __attribute__((ext_vector_type(4))) float f32x4;
typedef unsigned short ushortT;

#define Bn 4
#define Hn 128
#define Wn 128
#define HP 130
#define WP 130
#define HW (Hn * Wn)

#define XP_ELEMS (Bn * HP * WP * 64)   // ushorts
#define WCAT_ELEMS (64 * 576)

__device__ __forceinline__ ushortT f2bf_u(float f) {
    unsigned int u = __float_as_uint(f);
    return (ushortT)((u + 0x8000u) >> 16);   // round-half-up to bf16
}

// ---------------------------------------------------------------------------
// prep3 (unchanged from r6):
//  blocks [0,1024)      : interior NHWC bf16 pad-transpose, 64 pixels x 64 ch
//  blocks [1024,1152)   : zero the 130x130 borders
//  blocks [1152,1296)   : repack wcat   (wcatB[ch][kpos*64+c])
//  blocks [1296,1440)   : repack wreg   (wregB[o][kpos*64+c])
// ---------------------------------------------------------------------------
__global__ __launch_bounds__(256) void prep3(
    const float* __restrict__ x,
    const float* __restrict__ w1, const float* __restrict__ w2,
    const float* __restrict__ wo, const float* __restrict__ wm,
    const float* __restrict__ wr,
    ushortT* __restrict__ xp, ushortT* __restrict__ wcatB, ushortT* __restrict__ wregB)
{
    __shared__ float tl[64][69];
    int blk = blockIdx.x;
    int tid = threadIdx.x;

    if (blk < 1024) {
        int b = blk >> 8;
        int chunk = blk & 255;
        int hw0 = chunk << 6;          // 64-pixel chunk, fixed row
        int y = hw0 >> 7;              // source row
        int w0 = hw0 & 127;            // 0 or 64
        const float* xb = x + (size_t)b * 64 * HW + hw0;
        for (int i = tid; i < 4096; i += 256) {
            int c = i >> 6, w = i & 63;               // coalesced 256B in w
            tl[w][c] = xb[(size_t)c * HW + w];
        }
        __syncthreads();
        uint2* dst = (uint2*)(xp + ((size_t)(b * HP + y + 1) * WP + (w0 + 1)) * 64);
        for (int j = tid; j < 1024; j += 256) {       // consecutive j -> consecutive addr
            int w = j >> 4, cp = j & 15;
            uint2 u;
            u.x = (uint)f2bf_u(tl[w][4 * cp])     | ((uint)f2bf_u(tl[w][4 * cp + 1]) << 16);
            u.y = (uint)f2bf_u(tl[w][4 * cp + 2]) | ((uint)f2bf_u(tl[w][4 * cp + 3]) << 16);
            dst[j] = u;
        }
    } else if (blk < 1152) {
        int idx = (blk - 1024) * 256 + tid;           // [0, 32768)
        if (idx < 16512) {
            int b, y, w, e;
            if (idx < 8320) {                         // rows y=0,129 (130 px each)
                int p = idx >> 3; e = idx & 7;
                b = p / 260; int rr = p - b * 260;
                y = (rr < 130) ? 0 : (HP - 1);
                w = (rr < 130) ? rr : (rr - 130);
            } else {                                  // cols w=0,129, y=1..128
                int g = idx - 8320;
                int p = g >> 3; e = g & 7;
                b = p >> 8; int rr = p & 255;
                y = 1 + (rr & 127);
                w = (rr < 128) ? 0 : (WP - 1);
            }
            uint4 z = {0u, 0u, 0u, 0u};
            ((uint4*)xp)[((size_t)(b * HP + y) * WP + w) * 8 + e] = z;
        }
    } else if (blk < 1296) {
        int t = (blk - 1152) * 256 + tid;             // 0..36863
        int ch = t / 576;
        int k = t - ch * 576;
        int kpos = k >> 6, c = k & 63;
        float v = 0.f;
        if (ch < 18)      v = w1[(ch * 64 + c) * 9 + kpos];
        else if (ch < 36) v = w2[((ch - 18) * 64 + c) * 9 + kpos];
        else if (ch < 54) v = wo[((ch - 36) * 64 + c) * 9 + kpos];
        else if (ch < 63) v = wm[((ch - 54) * 64 + c) * 9 + kpos];
        wcatB[t] = f2bf_u(v);
    } else {
        int t = (blk - 1296) * 256 + tid;
        int o = t / 576;
        int k = t - o * 576;
        int kpos = k >> 6, c = k & 63;
        wregB[t] = f2bf_u(wr[(o * 64 + c) * 9 + kpos]);
    }
}

// ---------------------------------------------------------------------------
// fusedO: 256 thr = 4 waves x 16 pixels = 64 pixels/block. Grid 1024
// (exactly 4 blocks/CU, 4 waves/SIMD with __launch_bounds__(256,4)).
// LDS: Cls [64][65] f32 UNIONed with corner tables (gating reads Cls into
// regs, barrier, overwrites with tables).
// MFMA 16x16x32 bf16: A row=lane&15,k=(lane>>4)*8+j; B col=lane&15 same k;
// D col=lane&15, row=(lane>>4)*4+reg.
// ---------------------------------------------------------------------------
__global__ __launch_bounds__(256, 4) void fusedO(
    const ushortT* __restrict__ xp, const float* __restrict__ eps,
    const float* __restrict__ b1, const float* __restrict__ b2,
    const float* __restrict__ bo, const float* __restrict__ bm,
    const ushortT* __restrict__ wcatB, const ushortT* __restrict__ wregB,
    float* __restrict__ out)
{
    __shared__ __align__(16) char u_lds[9 * 64 * 32];          // 18432 B
    float*  Cls   = (float*)u_lds;                             // [64][65] (16640 B)
    int4*   cOffL = (int4*)u_lds;                              // [9][64]  (9216 B)
    float4* cWgtL = (float4*)(u_lds + 9 * 64 * 16);            // [9][64]  (9216 B)

    // bijective XCD swizzle: 1024 % 8 == 0
    int bid = blockIdx.x;
    int blk = (bid & 7) * 128 + (bid >> 3);
    int half = blk & 1;
    int h = (blk >> 1) & 127;
    int b = blk >> 8;
    int tid = threadIdx.x;
    int l = tid & 63;
    int wv = tid >> 6;
    int lane15 = l & 15;
    int g4 = l >> 4;
    int kl8 = g4 << 3;
    int pL0 = wv << 4;                  // block-local pixel base of this wave
    int wbase = half * 64;              // global w of block pixel 0

    const f32x4 zero4 = {0.f, 0.f, 0.f, 0.f};
    f32x4 acc[4];
#pragma unroll
    for (int mt = 0; mt < 4; ++mt) acc[mt] = zero4;

    // ---------------- Phase 1: conv GEMM (M=64, N=16/wave, K=576) ----------
#pragma unroll
    for (int kpos = 0; kpos < 9; ++kpos) {
        const int ky = kpos / 3, kx = kpos % 3;
        const ushortT* arow = wcatB + kpos * 64 + kl8;
        const ushortT* xrow = xp + (size_t)(b * HP + h + ky) * (WP * 64);

        bf16x8 afr[4][2];
#pragma unroll
        for (int mt = 0; mt < 4; ++mt)
#pragma unroll
            for (int ks = 0; ks < 2; ++ks)
                afr[mt][ks] = *(const bf16x8*)(arow + (mt * 16 + lane15) * 576 + ks * 32);

        const ushortT* bp = xrow + (size_t)(wbase + pL0 + lane15 + kx) * 64 + kl8;
        bf16x8 bfr[2];
        bfr[0] = *(const bf16x8*)(bp);
        bfr[1] = *(const bf16x8*)(bp + 32);

#pragma unroll
        for (int ks = 0; ks < 2; ++ks)
#pragma unroll
            for (int mt = 0; mt < 4; ++mt)
                acc[mt] = __builtin_amdgcn_mfma_f32_16x16x32_bf16(afr[mt][ks], bfr[ks], acc[mt], 0, 0, 0);
    }

    // conv C -> LDS transposed [pixL][ch]
#pragma unroll
    for (int mt = 0; mt < 4; ++mt)
#pragma unroll
        for (int r = 0; r < 4; ++r)
            Cls[(pL0 + lane15) * 65 + mt * 16 + g4 * 4 + r] = acc[mt][r];
    __syncthreads();

    // ---------------- Phase 2: gating. 576 items (9k x 64 pixL). ----------
    // Step A: read 7 conv values + 2 eps per item into regs (Cls is unioned
    // with the tables, so ALL reads must precede the barrier).
    float rA[3][7];
    float eA[3][2];
#pragma unroll
    for (int it = 0; it < 3; ++it) {
        int item = it * 256 + tid;
        if (item < 576) {
            int k = item >> 6;
            int pix = item & 63;
            const float* crow = Cls + pix * 65;
            rA[it][0] = crow[2 * k];
            rA[it][1] = crow[2 * k + 1];
            rA[it][2] = crow[18 + 2 * k];
            rA[it][3] = crow[19 + 2 * k];
            rA[it][4] = crow[36 + 2 * k];
            rA[it][5] = crow[37 + 2 * k];
            rA[it][6] = crow[54 + k];
            int w = wbase + pix;
            eA[it][0] = eps[((size_t)(b * 18 + 2 * k) * Hn + h) * Wn + w];
            eA[it][1] = eps[((size_t)(b * 18 + 2 * k + 1) * Hn + h) * Wn + w];
        }
    }
    __syncthreads();

    // Step B: compute coords/weights, write tables (overwrites Cls region).
#pragma unroll
    for (int it = 0; it < 3; ++it) {
        int item = it * 256 + tid;
        if (item < 576) {
            int k = item >> 6;
            int pix = item & 63;
            int ky = k / 3, kx = k % 3;
            int w = wbase + pix;
            float offv[2];
#pragma unroll
            for (int d = 0; d < 2; ++d) {
                int ch = 2 * k + d;
                float mu = fmaxf(rA[it][d] + b1[ch], 0.f);
                float lv = fmaxf(rA[it][2 + d] + b2[ch], 0.f);
                float z  = fmaf(eA[it][d], __expf(0.5f * lv), mu);
                float gate = 1.f / (1.f + __expf(-z));
                offv[d] = (rA[it][4 + d] + bo[ch]) * gate;
            }
            float m = 2.f / (1.f + __expf(-(rA[it][6] + bm[k])));
            float py = (float)(h + ky - 1) + offv[0];
            float px = (float)(w + kx - 1) + offv[1];
            float y0f = floorf(py), x0f = floorf(px);
            float ly = py - y0f, lx = px - x0f;
            int y0 = (int)y0f, x0 = (int)x0f;
            int y1 = y0 + 1, x1 = x0 + 1;
            bool okY0 = (y0 >= 0) & (y0 < Hn);
            bool okY1 = (y1 >= 0) & (y1 < Hn);
            bool okX0 = (x0 >= 0) & (x0 < Wn);
            bool okX1 = (x1 >= 0) & (x1 < Wn);
            int y0c = min(max(y0, 0), Hn - 1) + 1, y1c = min(max(y1, 0), Hn - 1) + 1;
            int x0c = min(max(x0, 0), Wn - 1) + 1, x1c = min(max(x1, 0), Wn - 1) + 1;
            int rb = b * HP;
            int4 co;
            co.x = ((rb + y0c) * WP + x0c) * 64;
            co.y = ((rb + y0c) * WP + x1c) * 64;
            co.z = ((rb + y1c) * WP + x0c) * 64;
            co.w = ((rb + y1c) * WP + x1c) * 64;
            float4 wq;
            wq.x = (1.f - ly) * (1.f - lx) * ((okY0 & okX0) ? m : 0.f);
            wq.y = (1.f - ly) * lx         * ((okY0 & okX1) ? m : 0.f);
            wq.z = ly * (1.f - lx)         * ((okY1 & okX0) ? m : 0.f);
            wq.w = ly * lx                 * ((okY1 & okX1) ? m : 0.f);
            cOffL[k * 64 + pix] = co;
            cWgtL[k * 64 + pix] = wq;
        }
    }
    __syncthreads();

    // ---------------- Phase 3: gather + deform GEMM ----------------
    f32x4 dcc[4];
#pragma unroll
    for (int mt = 0; mt < 4; ++mt) dcc[mt] = zero4;

#pragma unroll
    for (int kpos = 0; kpos < 9; ++kpos) {
        const ushortT* arow = wregB + kpos * 64 + kl8;
        bf16x8 afr[4][2];
#pragma unroll
        for (int mt = 0; mt < 4; ++mt)
#pragma unroll
            for (int ks = 0; ks < 2; ++ks)
                afr[mt][ks] = *(const bf16x8*)(arow + (mt * 16 + lane15) * 576 + ks * 32);

        int4 co   = cOffL[kpos * 64 + pL0 + lane15];
        float4 wq = cWgtL[kpos * 64 + pL0 + lane15];
        bf16x8 v00[2], v01[2], v10[2], v11[2];
#pragma unroll
        for (int ks = 0; ks < 2; ++ks) {
            int cofs = ks * 32 + kl8;
            v00[ks] = *(const bf16x8*)(xp + co.x + cofs);
            v01[ks] = *(const bf16x8*)(xp + co.y + cofs);
            v10[ks] = *(const bf16x8*)(xp + co.z + cofs);
            v11[ks] = *(const bf16x8*)(xp + co.w + cofs);
        }
#pragma unroll
        for (int ks = 0; ks < 2; ++ks) {
            bf16x8 bfr;
#pragma unroll
            for (int j = 0; j < 8; ++j) {
                float f = wq.x * (float)v00[ks][j];
                f = fmaf(wq.y, (float)v01[ks][j], f);
                f = fmaf(wq.z, (float)v10[ks][j], f);
                f = fmaf(wq.w, (float)v11[ks][j], f);
                bfr[j] = (__bf16)f;
            }
#pragma unroll
            for (int mt = 0; mt < 4; ++mt)
                dcc[mt] = __builtin_amdgcn_mfma_f32_16x16x32_bf16(afr[mt][ks], bfr, dcc[mt], 0, 0, 0);
        }
    }

    // ---------------- Phase 4: write out ----------------
#pragma unroll
    for (int mt = 0; mt < 4; ++mt)
#pragma unroll
        for (int r = 0; r < 4; ++r) {
            int o = mt * 16 + g4 * 4 + r;
            out[((size_t)(b * 64 + o) * Hn + h) * Wn + wbase + pL0 + lane15] = dcc[mt][r];
        }
}

// ---------------------------------------------------------------------------
extern "C" void kernel_launch(void* const* d_in, const int* in_sizes, int n_in,
                              void* d_out, int out_size, void* d_ws, size_t ws_size,
                              hipStream_t stream) {
    const float* x     = (const float*)d_in[0];
    const float* eps   = (const float*)d_in[1];
    const float* w_fc1 = (const float*)d_in[2];
    const float* b_fc1 = (const float*)d_in[3];
    const float* w_fc2 = (const float*)d_in[4];
    const float* b_fc2 = (const float*)d_in[5];
    const float* w_off = (const float*)d_in[6];
    const float* b_off = (const float*)d_in[7];
    const float* w_mod = (const float*)d_in[8];
    const float* b_mod = (const float*)d_in[9];
    const float* w_reg = (const float*)d_in[10];

    ushortT* xp    = (ushortT*)d_ws;
    ushortT* wcatB = xp + XP_ELEMS;
    ushortT* wregB = wcatB + WCAT_ELEMS;

    prep3<<<1440, 256, 0, stream>>>(x, w_fc1, w_fc2, w_off, w_mod, w_reg,
                                    xp, wcatB, wregB);
    fusedO<<<1024, 256, 0, stream>>>(xp, eps, b_fc1, b_fc2, b_off, b_mod,
                                     wcatB, wregB, (float*)d_out);
}

// Round 8
// 144.343 us; speedup vs baseline: 1.3488x; 1.3488x over previous
//
#include <hip/hip_runtime.h>

typedef __attribute__((ext_vector_type(8))) __bf16 bf16x8;
typedef __attribute__((ext_vector_type(4))) float f32x4;
typedef unsigned short ushortT;

#define Bn 4
#define Hn 128
#define Wn 128
#define HP 130
#define WP 130
#define HW (Hn * Wn)

#define XP_ELEMS (Bn * HP * WP * 64)   // ushorts
#define WCAT_ELEMS (64 * 576)

__device__ __forceinline__ ushortT f2bf_u(float f) {
    unsigned int u = __float_as_uint(f);
    return (ushortT)((u + 0x8000u) >> 16);   // round-half-up to bf16
}

// ---------------------------------------------------------------------------
// prep4:
//  blocks [0,1024)      : interior NHWC bf16 pad-transpose, 64 pixels x 64 ch
//  blocks [1024,1152)   : zero the 130x130 borders
//  blocks [1152,1296)   : wcatF fragment-linear   (see below)
//  blocks [1296,1440)   : wregF fragment-linear
//
// Fragment-linear A layout for mfma_f32_16x16x32_bf16:
//   element u = frag*512 + l*8 + j,  frag = (kpos*2+ks)*4+mt
//   ch = mt*16 + (l&15);  c = ks*32 + (l>>4)*8 + j
//   -> a wave's A-frag load is base + lane*16B, fully coalesced (1KB burst).
// ---------------------------------------------------------------------------
__global__ __launch_bounds__(256) void prep4(
    const float* __restrict__ x,
    const float* __restrict__ w1, const float* __restrict__ w2,
    const float* __restrict__ wo, const float* __restrict__ wm,
    const float* __restrict__ wr,
    ushortT* __restrict__ xp, ushortT* __restrict__ wcatF, ushortT* __restrict__ wregF)
{
    __shared__ float tl[64][69];
    int blk = blockIdx.x;
    int tid = threadIdx.x;

    if (blk < 1024) {
        int b = blk >> 8;
        int chunk = blk & 255;
        int hw0 = chunk << 6;          // 64-pixel chunk, fixed row
        int y = hw0 >> 7;              // source row
        int w0 = hw0 & 127;            // 0 or 64
        const float* xb = x + (size_t)b * 64 * HW + hw0;
        for (int i = tid; i < 4096; i += 256) {
            int c = i >> 6, w = i & 63;               // coalesced 256B in w
            tl[w][c] = xb[(size_t)c * HW + w];
        }
        __syncthreads();
        uint2* dst = (uint2*)(xp + ((size_t)(b * HP + y + 1) * WP + (w0 + 1)) * 64);
        for (int j = tid; j < 1024; j += 256) {       // consecutive j -> consecutive addr
            int w = j >> 4, cp = j & 15;
            uint2 u;
            u.x = (uint)f2bf_u(tl[w][4 * cp])     | ((uint)f2bf_u(tl[w][4 * cp + 1]) << 16);
            u.y = (uint)f2bf_u(tl[w][4 * cp + 2]) | ((uint)f2bf_u(tl[w][4 * cp + 3]) << 16);
            dst[j] = u;
        }
    } else if (blk < 1152) {
        int idx = (blk - 1024) * 256 + tid;           // [0, 32768)
        if (idx < 16512) {
            int b, y, w, e;
            if (idx < 8320) {                         // rows y=0,129 (130 px each)
                int p = idx >> 3; e = idx & 7;
                b = p / 260; int rr = p - b * 260;
                y = (rr < 130) ? 0 : (HP - 1);
                w = (rr < 130) ? rr : (rr - 130);
            } else {                                  // cols w=0,129, y=1..128
                int g = idx - 8320;
                int p = g >> 3; e = g & 7;
                b = p >> 8; int rr = p & 255;
                y = 1 + (rr & 127);
                w = (rr < 128) ? 0 : (WP - 1);
            }
            uint4 z = {0u, 0u, 0u, 0u};
            ((uint4*)xp)[((size_t)(b * HP + y) * WP + w) * 8 + e] = z;
        }
    } else if (blk < 1296) {
        int t = (blk - 1152) * 256 + tid;             // 0..36863
        int frag = t >> 9;
        int rem = t & 511;
        int l = rem >> 3, j = rem & 7;
        int kpos = frag >> 3;
        int ks = (frag >> 2) & 1;
        int mt = frag & 3;
        int ch = mt * 16 + (l & 15);
        int c = ks * 32 + (l >> 4) * 8 + j;
        float v = 0.f;
        if (ch < 18)      v = w1[(ch * 64 + c) * 9 + kpos];
        else if (ch < 36) v = w2[((ch - 18) * 64 + c) * 9 + kpos];
        else if (ch < 54) v = wo[((ch - 36) * 64 + c) * 9 + kpos];
        else if (ch < 63) v = wm[((ch - 54) * 64 + c) * 9 + kpos];
        wcatF[t] = f2bf_u(v);
    } else {
        int t = (blk - 1296) * 256 + tid;
        int frag = t >> 9;
        int rem = t & 511;
        int l = rem >> 3, j = rem & 7;
        int kpos = frag >> 3;
        int ks = (frag >> 2) & 1;
        int mt = frag & 3;
        int o = mt * 16 + (l & 15);
        int c = ks * 32 + (l >> 4) * 8 + j;
        wregF[t] = f2bf_u(wr[(o * 64 + c) * 9 + kpos]);
    }
}

// ---------------------------------------------------------------------------
// fusedP: r6 fusedN geometry (4 waves x 32 pixels = one 128-pixel row per
// block, grid 512, XCD swizzle, __launch_bounds__(256,2)); ONLY change:
// A-fragment loads are fragment-linear coalesced (base + lane*16B).
// MFMA 16x16x32 bf16: B col=lane&15, k=(lane>>4)*8+j;
// D col=lane&15, row=(lane>>4)*4+reg.
// ---------------------------------------------------------------------------
__global__ __launch_bounds__(256, 2) void fusedP(
    const ushortT* __restrict__ xp, const float* __restrict__ eps,
    const float* __restrict__ b1, const float* __restrict__ b2,
    const float* __restrict__ bo, const float* __restrict__ bm,
    const ushortT* __restrict__ wcatF, const ushortT* __restrict__ wregF,
    float* __restrict__ out)
{
    __shared__ float  Cls[128 * 65];    // conv results [pix][ch]
    __shared__ int4   cOffL[9 * 128];   // per (k,pix): 4 corner elem-offsets
    __shared__ float4 cWgtL[9 * 128];   // per (k,pix): bilinear*mask weights

    // bijective XCD swizzle: 512 % 8 == 0
    int bid = blockIdx.x;
    int blk = (bid & 7) * 64 + (bid >> 3);
    int h = blk & 127;
    int b = blk >> 7;
    int tid = threadIdx.x;
    int l = tid & 63;
    int wv = tid >> 6;
    int lane15 = l & 15;
    int g4 = l >> 4;
    int kl8 = g4 << 3;
    int p0 = wv << 5;                   // wave's pixel base (0..96)

    const bf16x8* WcF = (const bf16x8*)wcatF;
    const bf16x8* WrF = (const bf16x8*)wregF;

    const f32x4 zero4 = {0.f, 0.f, 0.f, 0.f};
    f32x4 acc[4][2];
#pragma unroll
    for (int mt = 0; mt < 4; ++mt) { acc[mt][0] = zero4; acc[mt][1] = zero4; }

    // ---------------- Phase 1: conv GEMM (M=64, N=32/wave, K=576) ----------
#pragma unroll
    for (int kpos = 0; kpos < 9; ++kpos) {
        const int ky = kpos / 3, kx = kpos % 3;
        const ushortT* xrow = xp + (size_t)(b * HP + h + ky) * (WP * 64);

        bf16x8 afr[4][2];
#pragma unroll
        for (int mt = 0; mt < 4; ++mt)
#pragma unroll
            for (int ks = 0; ks < 2; ++ks)
                afr[mt][ks] = WcF[(size_t)((kpos * 2 + ks) * 4 + mt) * 64 + l];

        bf16x8 bfr[2][2];
#pragma unroll
        for (int nt = 0; nt < 2; ++nt) {
            const ushortT* bp = xrow + (size_t)(p0 + nt * 16 + lane15 + kx) * 64 + kl8;
#pragma unroll
            for (int ks = 0; ks < 2; ++ks)
                bfr[nt][ks] = *(const bf16x8*)(bp + ks * 32);
        }

#pragma unroll
        for (int nt = 0; nt < 2; ++nt)
#pragma unroll
            for (int ks = 0; ks < 2; ++ks)
#pragma unroll
                for (int mt = 0; mt < 4; ++mt)
                    acc[mt][nt] = __builtin_amdgcn_mfma_f32_16x16x32_bf16(afr[mt][ks], bfr[nt][ks], acc[mt][nt], 0, 0, 0);
    }

    // conv C -> LDS transposed [pix][ch]
#pragma unroll
    for (int nt = 0; nt < 2; ++nt)
#pragma unroll
        for (int mt = 0; mt < 4; ++mt)
#pragma unroll
            for (int r = 0; r < 4; ++r)
                Cls[(p0 + nt * 16 + lane15) * 65 + mt * 16 + g4 * 4 + r] = acc[mt][nt][r];
    __syncthreads();

    // ---------------- Phase 2: gating, 1152 (k,pix) items over 256 threads --
#pragma unroll
    for (int kk = 0; kk < 5; ++kk) {
        int item = kk * 256 + tid;
        if (item < 1152) {
            int k = item >> 7;          // 0..8
            int pix = item & 127;
            int ky = k / 3, kx = k % 3;
            const float* crow = Cls + pix * 65;
            float offv[2];
#pragma unroll
            for (int d = 0; d < 2; ++d) {
                int ch = 2 * k + d;
                float mu = fmaxf(crow[ch] + b1[ch], 0.f);
                float lv = fmaxf(crow[18 + ch] + b2[ch], 0.f);
                float e  = eps[((size_t)(b * 18 + ch) * Hn + h) * Wn + pix];
                float z  = fmaf(e, __expf(0.5f * lv), mu);
                float gate = 1.f / (1.f + __expf(-z));
                offv[d] = (crow[36 + ch] + bo[ch]) * gate;
            }
            float m = 2.f / (1.f + __expf(-(crow[54 + k] + bm[k])));
            float py = (float)(h + ky - 1) + offv[0];
            float px = (float)(pix + kx - 1) + offv[1];
            float y0f = floorf(py), x0f = floorf(px);
            float ly = py - y0f, lx = px - x0f;
            int y0 = (int)y0f, x0 = (int)x0f;
            int y1 = y0 + 1, x1 = x0 + 1;
            bool okY0 = (y0 >= 0) & (y0 < Hn);
            bool okY1 = (y1 >= 0) & (y1 < Hn);
            bool okX0 = (x0 >= 0) & (x0 < Wn);
            bool okX1 = (x1 >= 0) & (x1 < Wn);
            int y0c = min(max(y0, 0), Hn - 1) + 1, y1c = min(max(y1, 0), Hn - 1) + 1;
            int x0c = min(max(x0, 0), Wn - 1) + 1, x1c = min(max(x1, 0), Wn - 1) + 1;
            int rb = b * HP;
            int4 co;
            co.x = ((rb + y0c) * WP + x0c) * 64;
            co.y = ((rb + y0c) * WP + x1c) * 64;
            co.z = ((rb + y1c) * WP + x0c) * 64;
            co.w = ((rb + y1c) * WP + x1c) * 64;
            float4 wq;
            wq.x = (1.f - ly) * (1.f - lx) * ((okY0 & okX0) ? m : 0.f);
            wq.y = (1.f - ly) * lx         * ((okY0 & okX1) ? m : 0.f);
            wq.z = ly * (1.f - lx)         * ((okY1 & okX0) ? m : 0.f);
            wq.w = ly * lx                 * ((okY1 & okX1) ? m : 0.f);
            cOffL[k * 128 + pix] = co;
            cWgtL[k * 128 + pix] = wq;
        }
    }
    __syncthreads();

    // ---------------- Phase 3: gather + deform GEMM ----------------
    f32x4 dcc[4][2];
#pragma unroll
    for (int mt = 0; mt < 4; ++mt) { dcc[mt][0] = zero4; dcc[mt][1] = zero4; }

#pragma unroll
    for (int kpos = 0; kpos < 9; ++kpos) {
        bf16x8 afr[4][2];
#pragma unroll
        for (int mt = 0; mt < 4; ++mt)
#pragma unroll
            for (int ks = 0; ks < 2; ++ks)
                afr[mt][ks] = WrF[(size_t)((kpos * 2 + ks) * 4 + mt) * 64 + l];

#pragma unroll
        for (int nt = 0; nt < 2; ++nt) {
            int pix = p0 + nt * 16 + lane15;
            int4 co   = cOffL[kpos * 128 + pix];
            float4 wq = cWgtL[kpos * 128 + pix];
            bf16x8 v00[2], v01[2], v10[2], v11[2];
#pragma unroll
            for (int ks = 0; ks < 2; ++ks) {
                int cofs = ks * 32 + kl8;
                v00[ks] = *(const bf16x8*)(xp + co.x + cofs);
                v01[ks] = *(const bf16x8*)(xp + co.y + cofs);
                v10[ks] = *(const bf16x8*)(xp + co.z + cofs);
                v11[ks] = *(const bf16x8*)(xp + co.w + cofs);
            }
#pragma unroll
            for (int ks = 0; ks < 2; ++ks) {
                bf16x8 bfr;
#pragma unroll
                for (int j = 0; j < 8; ++j) {
                    float f = wq.x * (float)v00[ks][j];
                    f = fmaf(wq.y, (float)v01[ks][j], f);
                    f = fmaf(wq.z, (float)v10[ks][j], f);
                    f = fmaf(wq.w, (float)v11[ks][j], f);
                    bfr[j] = (__bf16)f;
                }
#pragma unroll
                for (int mt = 0; mt < 4; ++mt)
                    dcc[mt][nt] = __builtin_amdgcn_mfma_f32_16x16x32_bf16(afr[mt][ks], bfr, dcc[mt][nt], 0, 0, 0);
            }
        }
    }

    // ---------------- Phase 4: write out ----------------
#pragma unroll
    for (int nt = 0; nt < 2; ++nt)
#pragma unroll
        for (int mt = 0; mt < 4; ++mt)
#pragma unroll
            for (int r = 0; r < 4; ++r) {
                int o = mt * 16 + g4 * 4 + r;
                out[((size_t)(b * 64 + o) * Hn + h) * Wn + p0 + nt * 16 + lane15] = dcc[mt][nt][r];
            }
}

// ---------------------------------------------------------------------------
extern "C" void kernel_launch(void* const* d_in, const int* in_sizes, int n_in,
                              void* d_out, int out_size, void* d_ws, size_t ws_size,
                              hipStream_t stream) {
    const float* x     = (const float*)d_in[0];
    const float* eps   = (const float*)d_in[1];
    const float* w_fc1 = (const float*)d_in[2];
    const float* b_fc1 = (const float*)d_in[3];
    const float* w_fc2 = (const float*)d_in[4];
    const float* b_fc2 = (const float*)d_in[5];
    const float* w_off = (const float*)d_in[6];
    const float* b_off = (const float*)d_in[7];
    const float* w_mod = (const float*)d_in[8];
    const float* b_mod = (const float*)d_in[9];
    const float* w_reg = (const float*)d_in[10];

    ushortT* xp    = (ushortT*)d_ws;
    ushortT* wcatF = xp + XP_ELEMS;
    ushortT* wregF = wcatF + WCAT_ELEMS;

    prep4<<<1440, 256, 0, stream>>>(x, w_fc1, w_fc2, w_off, w_mod, w_reg,
                                    xp, wcatF, wregF);
    fusedP<<<512, 256, 0, stream>>>(xp, eps, b_fc1, b_fc2, b_off, b_mod,
                                    wcatF, wregF, (float*)d_out);
}

// Round 9
// 143.446 us; speedup vs baseline: 1.3572x; 1.0063x over previous
//
#include <hip/hip_runtime.h>

typedef __attribute__((ext_vector_type(8))) __bf16 bf16x8;
typedef __attribute__((ext_vector_type(4))) float f32x4;
typedef unsigned short ushortT;

#define Bn 4
#define Hn 128
#define Wn 128
#define HP 130
#define WP 130
#define HW (Hn * Wn)

#define XP_ELEMS (Bn * HP * WP * 64)   // ushorts
#define WCAT_ELEMS (64 * 576)

// LDS tile geometry
#define TROWS 6
#define TCOLS 130
#define CSTRIDE 144                     // bytes per (row,col) cell (128B data, padded)
#define TILE_BYTES (TROWS * TCOLS * CSTRIDE)   // 112320
#define U2_BYTES (9 * 128 * 32)                // 36864 tables (union with Cls 33280)

__device__ __forceinline__ ushortT f2bf_u(float f) {
    unsigned int u = __float_as_uint(f);
    return (ushortT)((u + 0x8000u) >> 16);   // round-half-up to bf16
}

// ---------------------------------------------------------------------------
// prep4 (unchanged from r8): pad-transpose + border zero + fragment-linear
// weight packs. wcatF/wregF: elem = frag*512 + l*8 + j, frag=(kpos*2+ks)*4+mt,
// ch|o = mt*16+(l&15), c = ks*32+(l>>4)*8+j.
// ---------------------------------------------------------------------------
__global__ __launch_bounds__(256) void prep4(
    const float* __restrict__ x,
    const float* __restrict__ w1, const float* __restrict__ w2,
    const float* __restrict__ wo, const float* __restrict__ wm,
    const float* __restrict__ wr,
    ushortT* __restrict__ xp, ushortT* __restrict__ wcatF, ushortT* __restrict__ wregF)
{
    __shared__ float tl[64][69];
    int blk = blockIdx.x;
    int tid = threadIdx.x;

    if (blk < 1024) {
        int b = blk >> 8;
        int chunk = blk & 255;
        int hw0 = chunk << 6;
        int y = hw0 >> 7;
        int w0 = hw0 & 127;
        const float* xb = x + (size_t)b * 64 * HW + hw0;
        for (int i = tid; i < 4096; i += 256) {
            int c = i >> 6, w = i & 63;
            tl[w][c] = xb[(size_t)c * HW + w];
        }
        __syncthreads();
        uint2* dst = (uint2*)(xp + ((size_t)(b * HP + y + 1) * WP + (w0 + 1)) * 64);
        for (int j = tid; j < 1024; j += 256) {
            int w = j >> 4, cp = j & 15;
            uint2 u;
            u.x = (uint)f2bf_u(tl[w][4 * cp])     | ((uint)f2bf_u(tl[w][4 * cp + 1]) << 16);
            u.y = (uint)f2bf_u(tl[w][4 * cp + 2]) | ((uint)f2bf_u(tl[w][4 * cp + 3]) << 16);
            dst[j] = u;
        }
    } else if (blk < 1152) {
        int idx = (blk - 1024) * 256 + tid;
        if (idx < 16512) {
            int b, y, w, e;
            if (idx < 8320) {
                int p = idx >> 3; e = idx & 7;
                b = p / 260; int rr = p - b * 260;
                y = (rr < 130) ? 0 : (HP - 1);
                w = (rr < 130) ? rr : (rr - 130);
            } else {
                int g = idx - 8320;
                int p = g >> 3; e = g & 7;
                b = p >> 8; int rr = p & 255;
                y = 1 + (rr & 127);
                w = (rr < 128) ? 0 : (WP - 1);
            }
            uint4 z = {0u, 0u, 0u, 0u};
            ((uint4*)xp)[((size_t)(b * HP + y) * WP + w) * 8 + e] = z;
        }
    } else if (blk < 1296) {
        int t = (blk - 1152) * 256 + tid;
        int frag = t >> 9;
        int rem = t & 511;
        int l = rem >> 3, j = rem & 7;
        int kpos = frag >> 3;
        int ks = (frag >> 2) & 1;
        int mt = frag & 3;
        int ch = mt * 16 + (l & 15);
        int c = ks * 32 + (l >> 4) * 8 + j;
        float v = 0.f;
        if (ch < 18)      v = w1[(ch * 64 + c) * 9 + kpos];
        else if (ch < 36) v = w2[((ch - 18) * 64 + c) * 9 + kpos];
        else if (ch < 54) v = wo[((ch - 36) * 64 + c) * 9 + kpos];
        else if (ch < 63) v = wm[((ch - 54) * 64 + c) * 9 + kpos];
        wcatF[t] = f2bf_u(v);
    } else {
        int t = (blk - 1296) * 256 + tid;
        int frag = t >> 9;
        int rem = t & 511;
        int l = rem >> 3, j = rem & 7;
        int kpos = frag >> 3;
        int ks = (frag >> 2) & 1;
        int mt = frag & 3;
        int o = mt * 16 + (l & 15);
        int c = ks * 32 + (l >> 4) * 8 + j;
        wregF[t] = f2bf_u(wr[(o * 64 + c) * 9 + kpos]);
    }
}

// ---------------------------------------------------------------------------
// fusedQ: full-row block (128 px, 4 waves x 32 px, r8 wave layout).
// NEW: LDS tile of xp rows h-1..h+4 (all 130 cols). Phase-1 B and most
// phase-3 gathers become ds_reads; per-corner global fallback for rows
// outside the tile (encoded as negative offset).
// MFMA 16x16x32 bf16: B col=lane&15, k=(lane>>4)*8+j;
// D col=lane&15, row=(lane>>4)*4+reg.
// ---------------------------------------------------------------------------
__global__ __launch_bounds__(256, 1) void fusedQ(
    const ushortT* __restrict__ xp, const float* __restrict__ eps,
    const float* __restrict__ b1, const float* __restrict__ b2,
    const float* __restrict__ bo, const float* __restrict__ bm,
    const ushortT* __restrict__ wcatF, const ushortT* __restrict__ wregF,
    float* __restrict__ out)
{
    __shared__ __align__(16) char SH[TILE_BYTES + U2_BYTES];   // 149184 B
    char*   tile  = SH;
    int4*   cOffL = (int4*)(SH + TILE_BYTES);                  // [9][128]
    float4* cWgtL = (float4*)(SH + TILE_BYTES + 9 * 128 * 16); // [9][128]
    float*  Cls   = (float*)(SH + TILE_BYTES);                 // [128][65] union w/ tables

    // bijective XCD swizzle: 512 % 8 == 0
    int bid = blockIdx.x;
    int blk = (bid & 7) * 64 + (bid >> 3);
    int h = blk & 127;
    int b = blk >> 7;
    int tid = threadIdx.x;
    int l = tid & 63;
    int wv = tid >> 6;
    int lane15 = l & 15;
    int g4 = l >> 4;
    int kl8 = g4 << 3;
    int p0 = wv << 5;                   // wave's pixel base (0..96)

    const bf16x8* WcF = (const bf16x8*)wcatF;
    const bf16x8* WrF = (const bf16x8*)wregF;

    // ---------------- Phase 0: stage xp rows h-1..h+4 into LDS tile --------
#pragma unroll
    for (int i = 0; i < TROWS; ++i) {
        int ypad = h - 1 + i;
        if (ypad >= 0 && ypad <= 129) {
            const uint4* srow = (const uint4*)(xp + ((size_t)(b * HP + ypad) * WP) * 64);
            char* drow = tile + i * (TCOLS * CSTRIDE);
            for (int t2 = tid; t2 < TCOLS * 8; t2 += 256) {
                int cj = t2 >> 3, sub = t2 & 7;
                *(uint4*)(drow + cj * CSTRIDE + sub * 16) = srow[cj * 8 + sub];
            }
        }
    }
    __syncthreads();

    const f32x4 zero4 = {0.f, 0.f, 0.f, 0.f};
    f32x4 acc[4][2];
#pragma unroll
    for (int mt = 0; mt < 4; ++mt) { acc[mt][0] = zero4; acc[mt][1] = zero4; }

    // ---------------- Phase 1: conv GEMM; A global frag-linear, B from tile -
#pragma unroll
    for (int kpos = 0; kpos < 9; ++kpos) {
        const int ky = kpos / 3, kx = kpos % 3;

        bf16x8 afr[4][2];
#pragma unroll
        for (int mt = 0; mt < 4; ++mt)
#pragma unroll
            for (int ks = 0; ks < 2; ++ks)
                afr[mt][ks] = WcF[(size_t)((kpos * 2 + ks) * 4 + mt) * 64 + l];

        bf16x8 bfr[2][2];
#pragma unroll
        for (int nt = 0; nt < 2; ++nt) {
            int cell = (ky + 1) * TCOLS + (p0 + nt * 16 + lane15 + kx);
            const char* bp = tile + cell * CSTRIDE + g4 * 16;
            bfr[nt][0] = *(const bf16x8*)(bp);
            bfr[nt][1] = *(const bf16x8*)(bp + 64);
        }

#pragma unroll
        for (int nt = 0; nt < 2; ++nt)
#pragma unroll
            for (int ks = 0; ks < 2; ++ks)
#pragma unroll
                for (int mt = 0; mt < 4; ++mt)
                    acc[mt][nt] = __builtin_amdgcn_mfma_f32_16x16x32_bf16(afr[mt][ks], bfr[nt][ks], acc[mt][nt], 0, 0, 0);
    }

    // conv C -> LDS transposed [pix][ch] (Cls aliases tables; written fresh)
#pragma unroll
    for (int nt = 0; nt < 2; ++nt)
#pragma unroll
        for (int mt = 0; mt < 4; ++mt)
#pragma unroll
            for (int r = 0; r < 4; ++r)
                Cls[(p0 + nt * 16 + lane15) * 65 + mt * 16 + g4 * 4 + r] = acc[mt][nt][r];
    __syncthreads();

    // ---------------- Phase 2: gating. Step A: read Cls+eps to regs --------
    float rA[5][7];
    float eA[5][2];
#pragma unroll
    for (int kk = 0; kk < 5; ++kk) {
        int item = kk * 256 + tid;
        if (item < 1152) {
            int k = item >> 7;
            int pix = item & 127;
            const float* crow = Cls + pix * 65;
            rA[kk][0] = crow[2 * k];
            rA[kk][1] = crow[2 * k + 1];
            rA[kk][2] = crow[18 + 2 * k];
            rA[kk][3] = crow[19 + 2 * k];
            rA[kk][4] = crow[36 + 2 * k];
            rA[kk][5] = crow[37 + 2 * k];
            rA[kk][6] = crow[54 + k];
            eA[kk][0] = eps[((size_t)(b * 18 + 2 * k) * Hn + h) * Wn + pix];
            eA[kk][1] = eps[((size_t)(b * 18 + 2 * k + 1) * Hn + h) * Wn + pix];
        }
    }
    __syncthreads();

    // Step B: compute corner tables (overwrites Cls region).
#pragma unroll
    for (int kk = 0; kk < 5; ++kk) {
        int item = kk * 256 + tid;
        if (item < 1152) {
            int k = item >> 7;
            int pix = item & 127;
            int ky = k / 3, kx = k % 3;
            float offv[2];
#pragma unroll
            for (int d = 0; d < 2; ++d) {
                int ch = 2 * k + d;
                float mu = fmaxf(rA[kk][d] + b1[ch], 0.f);
                float lv = fmaxf(rA[kk][2 + d] + b2[ch], 0.f);
                float z  = fmaf(eA[kk][d], __expf(0.5f * lv), mu);
                float gate = 1.f / (1.f + __expf(-z));
                offv[d] = (rA[kk][4 + d] + bo[ch]) * gate;
            }
            float m = 2.f / (1.f + __expf(-(rA[kk][6] + bm[k])));
            float py = (float)(h + ky - 1) + offv[0];
            float px = (float)(pix + kx - 1) + offv[1];
            float y0f = floorf(py), x0f = floorf(px);
            float ly = py - y0f, lx = px - x0f;
            int y0 = (int)y0f, x0 = (int)x0f;
            int y1 = y0 + 1, x1 = x0 + 1;
            bool okY0 = (y0 >= 0) & (y0 < Hn);
            bool okY1 = (y1 >= 0) & (y1 < Hn);
            bool okX0 = (x0 >= 0) & (x0 < Wn);
            bool okX1 = (x1 >= 0) & (x1 < Wn);
            int y0c = min(max(y0, 0), Hn - 1) + 1, y1c = min(max(y1, 0), Hn - 1) + 1;
            int x0c = min(max(x0, 0), Wn - 1) + 1, x1c = min(max(x1, 0), Wn - 1) + 1;
            int rb = b * HP;
            // encode: in-tile -> LDS byte offset (>=0); else -(global elem off)
            int iy0 = y0c - (h - 1);
            int iy1 = y1c - (h - 1);
            bool in0 = (iy0 >= 0) & (iy0 < TROWS);
            bool in1 = (iy1 >= 0) & (iy1 < TROWS);
            int4 co;
            co.x = in0 ? (iy0 * TCOLS + x0c) * CSTRIDE : -(((rb + y0c) * WP + x0c) * 64);
            co.y = in0 ? (iy0 * TCOLS + x1c) * CSTRIDE : -(((rb + y0c) * WP + x1c) * 64);
            co.z = in1 ? (iy1 * TCOLS + x0c) * CSTRIDE : -(((rb + y1c) * WP + x0c) * 64);
            co.w = in1 ? (iy1 * TCOLS + x1c) * CSTRIDE : -(((rb + y1c) * WP + x1c) * 64);
            float4 wq;
            wq.x = (1.f - ly) * (1.f - lx) * ((okY0 & okX0) ? m : 0.f);
            wq.y = (1.f - ly) * lx         * ((okY0 & okX1) ? m : 0.f);
            wq.z = ly * (1.f - lx)         * ((okY1 & okX0) ? m : 0.f);
            wq.w = ly * lx                 * ((okY1 & okX1) ? m : 0.f);
            cOffL[k * 128 + pix] = co;
            cWgtL[k * 128 + pix] = wq;
        }
    }
    __syncthreads();

    // ---------------- Phase 3: gather (LDS fast path) + deform GEMM --------
    f32x4 dcc[4][2];
#pragma unroll
    for (int mt = 0; mt < 4; ++mt) { dcc[mt][0] = zero4; dcc[mt][1] = zero4; }

    int lofs = g4 * 16;                 // LDS sub-offset (bytes); +ks*64

#pragma unroll
    for (int kpos = 0; kpos < 9; ++kpos) {
        bf16x8 afr[4][2];
#pragma unroll
        for (int mt = 0; mt < 4; ++mt)
#pragma unroll
            for (int ks = 0; ks < 2; ++ks)
                afr[mt][ks] = WrF[(size_t)((kpos * 2 + ks) * 4 + mt) * 64 + l];

#pragma unroll
        for (int nt = 0; nt < 2; ++nt) {
            int pix = p0 + nt * 16 + lane15;
            int4 co   = cOffL[kpos * 128 + pix];
            float4 wq = cWgtL[kpos * 128 + pix];
            bf16x8 v00[2], v01[2], v10[2], v11[2];
            int m4 = min(min(co.x, co.y), min(co.z, co.w));
            if (__all(m4 >= 0)) {
#pragma unroll
                for (int ks = 0; ks < 2; ++ks) {
                    int o2 = lofs + ks * 64;
                    v00[ks] = *(const bf16x8*)(tile + co.x + o2);
                    v01[ks] = *(const bf16x8*)(tile + co.y + o2);
                    v10[ks] = *(const bf16x8*)(tile + co.z + o2);
                    v11[ks] = *(const bf16x8*)(tile + co.w + o2);
                }
            } else {
#pragma unroll
                for (int ks = 0; ks < 2; ++ks) {
                    int o2 = lofs + ks * 64;
                    int cofs = ks * 32 + kl8;
                    if (co.x >= 0) v00[ks] = *(const bf16x8*)(tile + co.x + o2);
                    else           v00[ks] = *(const bf16x8*)(xp + (-co.x) + cofs);
                    if (co.y >= 0) v01[ks] = *(const bf16x8*)(tile + co.y + o2);
                    else           v01[ks] = *(const bf16x8*)(xp + (-co.y) + cofs);
                    if (co.z >= 0) v10[ks] = *(const bf16x8*)(tile + co.z + o2);
                    else           v10[ks] = *(const bf16x8*)(xp + (-co.z) + cofs);
                    if (co.w >= 0) v11[ks] = *(const bf16x8*)(tile + co.w + o2);
                    else           v11[ks] = *(const bf16x8*)(xp + (-co.w) + cofs);
                }
            }
#pragma unroll
            for (int ks = 0; ks < 2; ++ks) {
                bf16x8 bfr;
#pragma unroll
                for (int j = 0; j < 8; ++j) {
                    float f = wq.x * (float)v00[ks][j];
                    f = fmaf(wq.y, (float)v01[ks][j], f);
                    f = fmaf(wq.z, (float)v10[ks][j], f);
                    f = fmaf(wq.w, (float)v11[ks][j], f);
                    bfr[j] = (__bf16)f;
                }
#pragma unroll
                for (int mt = 0; mt < 4; ++mt)
                    dcc[mt][nt] = __builtin_amdgcn_mfma_f32_16x16x32_bf16(afr[mt][ks], bfr, dcc[mt][nt], 0, 0, 0);
            }
        }
    }

    // ---------------- Phase 4: write out ----------------
#pragma unroll
    for (int nt = 0; nt < 2; ++nt)
#pragma unroll
        for (int mt = 0; mt < 4; ++mt)
#pragma unroll
            for (int r = 0; r < 4; ++r) {
                int o = mt * 16 + g4 * 4 + r;
                out[((size_t)(b * 64 + o) * Hn + h) * Wn + p0 + nt * 16 + lane15] = dcc[mt][nt][r];
            }
}

// ---------------------------------------------------------------------------
extern "C" void kernel_launch(void* const* d_in, const int* in_sizes, int n_in,
                              void* d_out, int out_size, void* d_ws, size_t ws_size,
                              hipStream_t stream) {
    const float* x     = (const float*)d_in[0];
    const float* eps   = (const float*)d_in[1];
    const float* w_fc1 = (const float*)d_in[2];
    const float* b_fc1 = (const float*)d_in[3];
    const float* w_fc2 = (const float*)d_in[4];
    const float* b_fc2 = (const float*)d_in[5];
    const float* w_off = (const float*)d_in[6];
    const float* b_off = (const float*)d_in[7];
    const float* w_mod = (const float*)d_in[8];
    const float* b_mod = (const float*)d_in[9];
    const float* w_reg = (const float*)d_in[10];

    ushortT* xp    = (ushortT*)d_ws;
    ushortT* wcatF = xp + XP_ELEMS;
    ushortT* wregF = wcatF + WCAT_ELEMS;

    prep4<<<1440, 256, 0, stream>>>(x, w_fc1, w_fc2, w_off, w_mod, w_reg,
                                    xp, wcatF, wregF);
    fusedQ<<<512, 256, 0, stream>>>(xp, eps, b_fc1, b_fc2, b_off, b_mod,
                                    wcatF, wregF, (float*)d_out);
}

// Round 10
// 131.851 us; speedup vs baseline: 1.4766x; 1.0879x over previous
//
#include <hip/hip_runtime.h>

typedef __attribute__((ext_vector_type(8))) __bf16 bf16x8;
typedef __attribute__((ext_vector_type(4))) float f32x4;
typedef unsigned short ushortT;

#define Bn 4
#define Hn 128
#define Wn 128
#define HP 130
#define WP 130
#define HW (Hn * Wn)

#define XP_ELEMS (Bn * HP * WP * 64)   // ushorts
#define WCAT_ELEMS (64 * 576)

// LDS tile geometry
#define TROWS 6
#define TCOLS 130
#define CSTRIDE 144                     // bytes per (row,col) cell (128B data, padded)
#define TILE_BYTES (TROWS * TCOLS * CSTRIDE)   // 112320
#define U2_BYTES (9 * 128 * 32)                // 36864 tables (union with Cls 33280)

__device__ __forceinline__ ushortT f2bf_u(float f) {
    unsigned int u = __float_as_uint(f);
    return (ushortT)((u + 0x8000u) >> 16);   // round-half-up to bf16
}

// ---------------------------------------------------------------------------
// prep4 (unchanged from r8): pad-transpose + border zero + fragment-linear
// weight packs. wcatF/wregF: elem = frag*512 + l*8 + j, frag=(kpos*2+ks)*4+mt,
// ch|o = mt*16+(l&15), c = ks*32+(l>>4)*8+j.
// ---------------------------------------------------------------------------
__global__ __launch_bounds__(256) void prep4(
    const float* __restrict__ x,
    const float* __restrict__ w1, const float* __restrict__ w2,
    const float* __restrict__ wo, const float* __restrict__ wm,
    const float* __restrict__ wr,
    ushortT* __restrict__ xp, ushortT* __restrict__ wcatF, ushortT* __restrict__ wregF)
{
    __shared__ float tl[64][69];
    int blk = blockIdx.x;
    int tid = threadIdx.x;

    if (blk < 1024) {
        int b = blk >> 8;
        int chunk = blk & 255;
        int hw0 = chunk << 6;
        int y = hw0 >> 7;
        int w0 = hw0 & 127;
        const float* xb = x + (size_t)b * 64 * HW + hw0;
        for (int i = tid; i < 4096; i += 256) {
            int c = i >> 6, w = i & 63;
            tl[w][c] = xb[(size_t)c * HW + w];
        }
        __syncthreads();
        uint2* dst = (uint2*)(xp + ((size_t)(b * HP + y + 1) * WP + (w0 + 1)) * 64);
        for (int j = tid; j < 1024; j += 256) {
            int w = j >> 4, cp = j & 15;
            uint2 u;
            u.x = (uint)f2bf_u(tl[w][4 * cp])     | ((uint)f2bf_u(tl[w][4 * cp + 1]) << 16);
            u.y = (uint)f2bf_u(tl[w][4 * cp + 2]) | ((uint)f2bf_u(tl[w][4 * cp + 3]) << 16);
            dst[j] = u;
        }
    } else if (blk < 1152) {
        int idx = (blk - 1024) * 256 + tid;
        if (idx < 16512) {
            int b, y, w, e;
            if (idx < 8320) {
                int p = idx >> 3; e = idx & 7;
                b = p / 260; int rr = p - b * 260;
                y = (rr < 130) ? 0 : (HP - 1);
                w = (rr < 130) ? rr : (rr - 130);
            } else {
                int g = idx - 8320;
                int p = g >> 3; e = g & 7;
                b = p >> 8; int rr = p & 255;
                y = 1 + (rr & 127);
                w = (rr < 128) ? 0 : (WP - 1);
            }
            uint4 z = {0u, 0u, 0u, 0u};
            ((uint4*)xp)[((size_t)(b * HP + y) * WP + w) * 8 + e] = z;
        }
    } else if (blk < 1296) {
        int t = (blk - 1152) * 256 + tid;
        int frag = t >> 9;
        int rem = t & 511;
        int l = rem >> 3, j = rem & 7;
        int kpos = frag >> 3;
        int ks = (frag >> 2) & 1;
        int mt = frag & 3;
        int ch = mt * 16 + (l & 15);
        int c = ks * 32 + (l >> 4) * 8 + j;
        float v = 0.f;
        if (ch < 18)      v = w1[(ch * 64 + c) * 9 + kpos];
        else if (ch < 36) v = w2[((ch - 18) * 64 + c) * 9 + kpos];
        else if (ch < 54) v = wo[((ch - 36) * 64 + c) * 9 + kpos];
        else if (ch < 63) v = wm[((ch - 54) * 64 + c) * 9 + kpos];
        wcatF[t] = f2bf_u(v);
    } else {
        int t = (blk - 1296) * 256 + tid;
        int frag = t >> 9;
        int rem = t & 511;
        int l = rem >> 3, j = rem & 7;
        int kpos = frag >> 3;
        int ks = (frag >> 2) & 1;
        int mt = frag & 3;
        int o = mt * 16 + (l & 15);
        int c = ks * 32 + (l >> 4) * 8 + j;
        wregF[t] = f2bf_u(wr[(o * 64 + c) * 9 + kpos]);
    }
}

// ---------------------------------------------------------------------------
// fusedR: 512 threads = 8 waves x 16 pixels = one 128-px row per block.
// Identical data paths to r9 fusedQ; only the wave decomposition changed
// (2 waves/SIMD at the same 149.5 KB LDS -> latency hiding).
// MFMA 16x16x32 bf16: A/B k=(lane>>4)*8+j (+ks*32); B col=lane&15;
// D col=lane&15, row=(lane>>4)*4+reg.
// ---------------------------------------------------------------------------
__global__ __launch_bounds__(512, 1) void fusedR(
    const ushortT* __restrict__ xp, const float* __restrict__ eps,
    const float* __restrict__ b1, const float* __restrict__ b2,
    const float* __restrict__ bo, const float* __restrict__ bm,
    const ushortT* __restrict__ wcatF, const ushortT* __restrict__ wregF,
    float* __restrict__ out)
{
    __shared__ __align__(16) char SH[TILE_BYTES + U2_BYTES];   // 149184 B
    char*   tile  = SH;
    int4*   cOffL = (int4*)(SH + TILE_BYTES);                  // [9][128]
    float4* cWgtL = (float4*)(SH + TILE_BYTES + 9 * 128 * 16); // [9][128]
    float*  Cls   = (float*)(SH + TILE_BYTES);                 // [128][65] union w/ tables

    // bijective XCD swizzle: 512 % 8 == 0
    int bid = blockIdx.x;
    int blk = (bid & 7) * 64 + (bid >> 3);
    int h = blk & 127;
    int b = blk >> 7;
    int tid = threadIdx.x;
    int l = tid & 63;
    int wv = tid >> 6;                  // 0..7
    int lane15 = l & 15;
    int g4 = l >> 4;
    int kl8 = g4 << 3;
    int p0 = wv << 4;                   // wave's pixel base (0..112)

    const bf16x8* WcF = (const bf16x8*)wcatF;
    const bf16x8* WrF = (const bf16x8*)wregF;

    // ---------------- Phase 0: stage xp rows h-1..h+4 into LDS tile --------
#pragma unroll
    for (int i = 0; i < TROWS; ++i) {
        int ypad = h - 1 + i;
        if (ypad >= 0 && ypad <= 129) {
            const uint4* srow = (const uint4*)(xp + ((size_t)(b * HP + ypad) * WP) * 64);
            char* drow = tile + i * (TCOLS * CSTRIDE);
            for (int t2 = tid; t2 < TCOLS * 8; t2 += 512) {
                int cj = t2 >> 3, sub = t2 & 7;
                *(uint4*)(drow + cj * CSTRIDE + sub * 16) = srow[cj * 8 + sub];
            }
        }
    }
    __syncthreads();

    const f32x4 zero4 = {0.f, 0.f, 0.f, 0.f};
    f32x4 acc[4];
#pragma unroll
    for (int mt = 0; mt < 4; ++mt) acc[mt] = zero4;

    // ---------------- Phase 1: conv GEMM; A global frag-linear, B from tile -
#pragma unroll
    for (int kpos = 0; kpos < 9; ++kpos) {
        const int ky = kpos / 3, kx = kpos % 3;

        bf16x8 afr[4][2];
#pragma unroll
        for (int mt = 0; mt < 4; ++mt)
#pragma unroll
            for (int ks = 0; ks < 2; ++ks)
                afr[mt][ks] = WcF[(size_t)((kpos * 2 + ks) * 4 + mt) * 64 + l];

        int cell = (ky + 1) * TCOLS + (p0 + lane15 + kx);
        const char* bp = tile + cell * CSTRIDE + g4 * 16;
        bf16x8 bfr[2];
        bfr[0] = *(const bf16x8*)(bp);
        bfr[1] = *(const bf16x8*)(bp + 64);

#pragma unroll
        for (int ks = 0; ks < 2; ++ks)
#pragma unroll
            for (int mt = 0; mt < 4; ++mt)
                acc[mt] = __builtin_amdgcn_mfma_f32_16x16x32_bf16(afr[mt][ks], bfr[ks], acc[mt], 0, 0, 0);
    }

    // conv C -> LDS transposed [pix][ch] (Cls aliases tables; written fresh)
#pragma unroll
    for (int mt = 0; mt < 4; ++mt)
#pragma unroll
        for (int r = 0; r < 4; ++r)
            Cls[(p0 + lane15) * 65 + mt * 16 + g4 * 4 + r] = acc[mt][r];
    __syncthreads();

    // ---------------- Phase 2: gating. Step A: read Cls+eps to regs --------
    float rA[3][7];
    float eA[3][2];
#pragma unroll
    for (int kk = 0; kk < 3; ++kk) {
        int item = kk * 512 + tid;
        if (item < 1152) {
            int k = item >> 7;
            int pix = item & 127;
            const float* crow = Cls + pix * 65;
            rA[kk][0] = crow[2 * k];
            rA[kk][1] = crow[2 * k + 1];
            rA[kk][2] = crow[18 + 2 * k];
            rA[kk][3] = crow[19 + 2 * k];
            rA[kk][4] = crow[36 + 2 * k];
            rA[kk][5] = crow[37 + 2 * k];
            rA[kk][6] = crow[54 + k];
            eA[kk][0] = eps[((size_t)(b * 18 + 2 * k) * Hn + h) * Wn + pix];
            eA[kk][1] = eps[((size_t)(b * 18 + 2 * k + 1) * Hn + h) * Wn + pix];
        }
    }
    __syncthreads();

    // Step B: compute corner tables (overwrites Cls region).
#pragma unroll
    for (int kk = 0; kk < 3; ++kk) {
        int item = kk * 512 + tid;
        if (item < 1152) {
            int k = item >> 7;
            int pix = item & 127;
            int ky = k / 3, kx = k % 3;
            float offv[2];
#pragma unroll
            for (int d = 0; d < 2; ++d) {
                int ch = 2 * k + d;
                float mu = fmaxf(rA[kk][d] + b1[ch], 0.f);
                float lv = fmaxf(rA[kk][2 + d] + b2[ch], 0.f);
                float z  = fmaf(eA[kk][d], __expf(0.5f * lv), mu);
                float gate = 1.f / (1.f + __expf(-z));
                offv[d] = (rA[kk][4 + d] + bo[ch]) * gate;
            }
            float m = 2.f / (1.f + __expf(-(rA[kk][6] + bm[k])));
            float py = (float)(h + ky - 1) + offv[0];
            float px = (float)(pix + kx - 1) + offv[1];
            float y0f = floorf(py), x0f = floorf(px);
            float ly = py - y0f, lx = px - x0f;
            int y0 = (int)y0f, x0 = (int)x0f;
            int y1 = y0 + 1, x1 = x0 + 1;
            bool okY0 = (y0 >= 0) & (y0 < Hn);
            bool okY1 = (y1 >= 0) & (y1 < Hn);
            bool okX0 = (x0 >= 0) & (x0 < Wn);
            bool okX1 = (x1 >= 0) & (x1 < Wn);
            int y0c = min(max(y0, 0), Hn - 1) + 1, y1c = min(max(y1, 0), Hn - 1) + 1;
            int x0c = min(max(x0, 0), Wn - 1) + 1, x1c = min(max(x1, 0), Wn - 1) + 1;
            int rb = b * HP;
            // encode: in-tile -> LDS byte offset (>=0); else -(global elem off)
            int iy0 = y0c - (h - 1);
            int iy1 = y1c - (h - 1);
            bool in0 = (iy0 >= 0) & (iy0 < TROWS);
            bool in1 = (iy1 >= 0) & (iy1 < TROWS);
            int4 co;
            co.x = in0 ? (iy0 * TCOLS + x0c) * CSTRIDE : -(((rb + y0c) * WP + x0c) * 64);
            co.y = in0 ? (iy0 * TCOLS + x1c) * CSTRIDE : -(((rb + y0c) * WP + x1c) * 64);
            co.z = in1 ? (iy1 * TCOLS + x0c) * CSTRIDE : -(((rb + y1c) * WP + x0c) * 64);
            co.w = in1 ? (iy1 * TCOLS + x1c) * CSTRIDE : -(((rb + y1c) * WP + x1c) * 64);
            float4 wq;
            wq.x = (1.f - ly) * (1.f - lx) * ((okY0 & okX0) ? m : 0.f);
            wq.y = (1.f - ly) * lx         * ((okY0 & okX1) ? m : 0.f);
            wq.z = ly * (1.f - lx)         * ((okY1 & okX0) ? m : 0.f);
            wq.w = ly * lx                 * ((okY1 & okX1) ? m : 0.f);
            cOffL[k * 128 + pix] = co;
            cWgtL[k * 128 + pix] = wq;
        }
    }
    __syncthreads();

    // ---------------- Phase 3: gather (LDS fast path) + deform GEMM --------
    f32x4 dcc[4];
#pragma unroll
    for (int mt = 0; mt < 4; ++mt) dcc[mt] = zero4;

    int lofs = g4 * 16;                 // LDS sub-offset (bytes); +ks*64

#pragma unroll
    for (int kpos = 0; kpos < 9; ++kpos) {
        bf16x8 afr[4][2];
#pragma unroll
        for (int mt = 0; mt < 4; ++mt)
#pragma unroll
            for (int ks = 0; ks < 2; ++ks)
                afr[mt][ks] = WrF[(size_t)((kpos * 2 + ks) * 4 + mt) * 64 + l];

        int pix = p0 + lane15;
        int4 co   = cOffL[kpos * 128 + pix];
        float4 wq = cWgtL[kpos * 128 + pix];
        bf16x8 v00[2], v01[2], v10[2], v11[2];
        int m4 = min(min(co.x, co.y), min(co.z, co.w));
        if (__all(m4 >= 0)) {
#pragma unroll
            for (int ks = 0; ks < 2; ++ks) {
                int o2 = lofs + ks * 64;
                v00[ks] = *(const bf16x8*)(tile + co.x + o2);
                v01[ks] = *(const bf16x8*)(tile + co.y + o2);
                v10[ks] = *(const bf16x8*)(tile + co.z + o2);
                v11[ks] = *(const bf16x8*)(tile + co.w + o2);
            }
        } else {
#pragma unroll
            for (int ks = 0; ks < 2; ++ks) {
                int o2 = lofs + ks * 64;
                int cofs = ks * 32 + kl8;
                if (co.x >= 0) v00[ks] = *(const bf16x8*)(tile + co.x + o2);
                else           v00[ks] = *(const bf16x8*)(xp + (-co.x) + cofs);
                if (co.y >= 0) v01[ks] = *(const bf16x8*)(tile + co.y + o2);
                else           v01[ks] = *(const bf16x8*)(xp + (-co.y) + cofs);
                if (co.z >= 0) v10[ks] = *(const bf16x8*)(tile + co.z + o2);
                else           v10[ks] = *(const bf16x8*)(xp + (-co.z) + cofs);
                if (co.w >= 0) v11[ks] = *(const bf16x8*)(tile + co.w + o2);
                else           v11[ks] = *(const bf16x8*)(xp + (-co.w) + cofs);
            }
        }
#pragma unroll
        for (int ks = 0; ks < 2; ++ks) {
            bf16x8 bfr;
#pragma unroll
            for (int j = 0; j < 8; ++j) {
                float f = wq.x * (float)v00[ks][j];
                f = fmaf(wq.y, (float)v01[ks][j], f);
                f = fmaf(wq.z, (float)v10[ks][j], f);
                f = fmaf(wq.w, (float)v11[ks][j], f);
                bfr[j] = (__bf16)f;
            }
#pragma unroll
            for (int mt = 0; mt < 4; ++mt)
                dcc[mt] = __builtin_amdgcn_mfma_f32_16x16x32_bf16(afr[mt][ks], bfr, dcc[mt], 0, 0, 0);
        }
    }

    // ---------------- Phase 4: write out ----------------
#pragma unroll
    for (int mt = 0; mt < 4; ++mt)
#pragma unroll
        for (int r = 0; r < 4; ++r) {
            int o = mt * 16 + g4 * 4 + r;
            out[((size_t)(b * 64 + o) * Hn + h) * Wn + p0 + lane15] = dcc[mt][r];
        }
}

// ---------------------------------------------------------------------------
extern "C" void kernel_launch(void* const* d_in, const int* in_sizes, int n_in,
                              void* d_out, int out_size, void* d_ws, size_t ws_size,
                              hipStream_t stream) {
    const float* x     = (const float*)d_in[0];
    const float* eps   = (const float*)d_in[1];
    const float* w_fc1 = (const float*)d_in[2];
    const float* b_fc1 = (const float*)d_in[3];
    const float* w_fc2 = (const float*)d_in[4];
    const float* b_fc2 = (const float*)d_in[5];
    const float* w_off = (const float*)d_in[6];
    const float* b_off = (const float*)d_in[7];
    const float* w_mod = (const float*)d_in[8];
    const float* b_mod = (const float*)d_in[9];
    const float* w_reg = (const float*)d_in[10];

    ushortT* xp    = (ushortT*)d_ws;
    ushortT* wcatF = xp + XP_ELEMS;
    ushortT* wregF = wcatF + WCAT_ELEMS;

    prep4<<<1440, 256, 0, stream>>>(x, w_fc1, w_fc2, w_off, w_mod, w_reg,
                                    xp, wcatF, wregF);
    fusedR<<<512, 512, 0, stream>>>(xp, eps, b_fc1, b_fc2, b_off, b_mod,
                                    wcatF, wregF, (float*)d_out);
}